// Round 4
// baseline (68.033 us; speedup 1.0000x reference)
//
#include <hip/hip_runtime.h>
#include <math.h>

#define D 64
#define NI 100
#define BSZ 64
#define LN_EPS 1e-5f
#define NIP 112            // padded j rows (7 tiles of 16)
#define IT 4               // i's per block
#define NT2 25             // i-tiles per batch
#define C2L 2.8853900817779268f   // 2*log2(e)

// ws layout (float indices):
#define OFF_W3GTT 0        // f32 [d][k] = w3[d,k]*g[k]            (4096)
#define OFF_W1B   4096     // bf16 [d][k] = w1[d,k]*C2L            (2048 f32 slots)
#define OFF_W2B   6144     // bf16 [d][k] = w2[d,k]*C2L            (2048)
#define OFF_W3G   8192     // f32 [64] sum_k w3[d,k]*g[k]
#define OFF_C0    8256     // f32 [64] C2L*(bij[d] + sum_k w3[d,k]*bln[k])
#define OFF_WSUMS 8320     // f32 [1] sum(wsum)

typedef __attribute__((ext_vector_type(8))) short bf8;
typedef __attribute__((ext_vector_type(4))) float f32x4;

// rounding f32->bf16
__device__ inline uint32_t f2bf(float x) {
  uint32_t u = __float_as_uint(x);
  return (u + 0x7fffu + ((u >> 16) & 1u)) >> 16;
}
__device__ inline int pk2(float a, float b) { return (int)(f2bf(a) | (f2bf(b) << 16)); }
// truncating pack (3 ops)
__device__ inline int pkt(float a, float b) {
  return (int)((__float_as_uint(a) >> 16) | (__float_as_uint(b) & 0xffff0000u));
}

// K0: fold/transpose weights once.
__global__ void k0_prep(const float* __restrict__ w_ij,
                        const float* __restrict__ g,
                        const float* __restrict__ bln,
                        const float* __restrict__ wsum,
                        const float* __restrict__ bij,
                        float* __restrict__ ws) {
  __shared__ float w_s[64 * 193];
  int tid = threadIdx.x;
  for (int idx = tid; idx < 64 * 192; idx += 256) {
    int dd = idx / 192, k = idx - dd * 192;
    w_s[dd * 193 + k] = w_ij[idx];
  }
  __syncthreads();
  for (int idx = tid; idx < 4096; idx += 256) {
    int dd = idx >> 6, k = idx & 63;
    ws[OFF_W3GTT + idx] = w_s[dd * 193 + 128 + k] * g[k];
  }
  uint32_t* w1b = (uint32_t*)(ws + OFF_W1B);
  uint32_t* w2b = (uint32_t*)(ws + OFF_W2B);
  for (int idx = tid; idx < 2048; idx += 256) {
    int dd = idx >> 5, kp = (idx & 31) * 2;
    w1b[idx] = pk2(w_s[dd * 193 + kp] * C2L,      w_s[dd * 193 + kp + 1] * C2L);
    w2b[idx] = pk2(w_s[dd * 193 + 64 + kp] * C2L, w_s[dd * 193 + 64 + kp + 1] * C2L);
  }
  if (tid < 64) {
    float wg = 0.f, wb = 0.f;
#pragma unroll
    for (int k = 0; k < 64; ++k) {
      float w = w_s[tid * 193 + 128 + k];
      wg = fmaf(w, g[k], wg);
      wb = fmaf(w, bln[k], wb);
    }
    ws[OFF_W3G + tid] = wg;
    ws[OFF_C0 + tid]  = C2L * (bij[tid] + wb);
  }
  if (tid == 0) {
    float s = 0.f;
    for (int k = 0; k < 64; ++k) s += wsum[k];
    ws[OFF_WSUMS] = s;
  }
}

// K2: one block per (b, 4-i tile); wave wv owns i = i0+wv end-to-end.
__global__ __launch_bounds__(256, 3) void k2_main(
    const float* __restrict__ emb,
    const float* __restrict__ gg,
    const float* __restrict__ bb,
    const float* __restrict__ wsum,
    const float* __restrict__ bsum,
    const float* __restrict__ ws,
    float* __restrict__ out) {
  int bid = blockIdx.x;
  int b = bid / NT2, itile = bid - b * NT2;
  int i0 = itile * IT;
  int tid = threadIdx.x;
  int wv = tid >> 6, lane = tid & 63, g = lane >> 4, c = lane & 15;
  int i = i0 + wv;

  __shared__ ushort E16[NIP * 64];     // bf16 e_j, swizzled
  __shared__ ushort E16SQ[NIP * 64];   // bf16 e_j^2
  __shared__ ushort LNE16[NIP * 64];   // bf16 LN(e_j)
  __shared__ float rs2_s[IT][NIP];     // C2L*rs
  __shared__ float mrs2_s[IT][NIP];    // -C2L*mu*rs
  __shared__ float z_s[IT][NIP];       // z then alpha

  const float* eb = emb + b * NI * D;

  // ---- stage: e, e^2, LN(e) (8 threads per row; shfl-width-8 stats) ----
  for (int u = tid; u < NIP * 8; u += 256) {
    int r = u >> 3, cb = u & 7, kk = cb * 8;
    int4 pe, ps, pl;
    if (r < NI) {
      const float* sp = eb + r * 64 + kk;
      float4 f0 = *(const float4*)sp, f1 = *(const float4*)(sp + 4);
      float s  = f0.x + f0.y + f0.z + f0.w + f1.x + f1.y + f1.z + f1.w;
      float s2 = f0.x*f0.x + f0.y*f0.y + f0.z*f0.z + f0.w*f0.w
               + f1.x*f1.x + f1.y*f1.y + f1.z*f1.z + f1.w*f1.w;
#pragma unroll
      for (int off = 1; off < 8; off <<= 1) {
        s  += __shfl_xor(s, off, 64);
        s2 += __shfl_xor(s2, off, 64);
      }
      float mu  = s * (1.f / 64.f);
      float var = s2 * (1.f / 64.f) - mu * mu;
      float rsv = rsqrtf(var + LN_EPS);
      float4 g0 = *(const float4*)(gg + kk), g1v = *(const float4*)(gg + kk + 4);
      float4 b0 = *(const float4*)(bb + kk), b1v = *(const float4*)(bb + kk + 4);
      float l0 = fmaf((f0.x - mu) * rsv, g0.x, b0.x);
      float l1 = fmaf((f0.y - mu) * rsv, g0.y, b0.y);
      float l2 = fmaf((f0.z - mu) * rsv, g0.z, b0.z);
      float l3 = fmaf((f0.w - mu) * rsv, g0.w, b0.w);
      float l4 = fmaf((f1.x - mu) * rsv, g1v.x, b1v.x);
      float l5 = fmaf((f1.y - mu) * rsv, g1v.y, b1v.y);
      float l6 = fmaf((f1.z - mu) * rsv, g1v.z, b1v.z);
      float l7 = fmaf((f1.w - mu) * rsv, g1v.w, b1v.w);
      pe.x = pkt(f0.x, f0.y); pe.y = pkt(f0.z, f0.w);
      pe.z = pkt(f1.x, f1.y); pe.w = pkt(f1.z, f1.w);
      ps.x = pkt(f0.x*f0.x, f0.y*f0.y); ps.y = pkt(f0.z*f0.z, f0.w*f0.w);
      ps.z = pkt(f1.x*f1.x, f1.y*f1.y); ps.w = pkt(f1.z*f1.z, f1.w*f1.w);
      pl.x = pkt(l0, l1); pl.y = pkt(l2, l3);
      pl.z = pkt(l4, l5); pl.w = pkt(l6, l7);
    } else {
      pe = make_int4(0,0,0,0); ps = pe; pl = pe;
    }
    int sw = (r * 128 + cb * 16) ^ ((r & 7) << 4);
    *(int4*)((char*)E16 + sw)   = pe;
    *(int4*)((char*)E16SQ + sw) = ps;
    *(int4*)((char*)LNE16 + sw) = pl;
  }
  __syncthreads();

  // ---- pb chain: pb'[i_local][d] = C2L * LN(e_i) . w2  (each wave redundantly) ----
  f32x4 apb[4];
#pragma unroll
  for (int n = 0; n < 4; ++n) apb[n] = (f32x4)0.f;
  {
    const ushort* w2b = (const ushort*)(ws + OFF_W2B);
#pragma unroll
    for (int s = 0; s < 2; ++s) {
      int r = i0 + c;
      int sw = (r * 128 + 16 * g + 64 * s) ^ ((r & 7) << 4);
      bf8 al = *(bf8*)((char*)LNE16 + sw);
#pragma unroll
      for (int n = 0; n < 4; ++n) {
        bf8 b2 = *(const bf8*)(w2b + (16 * n + c) * 64 + 8 * g + 32 * s);
        apb[n] = __builtin_amdgcn_mfma_f32_16x16x32_bf16(al, b2, apb[n], 0, 0, 0);
      }
    }
  }

  // ---- Gram stats (pure ds_read + MFMA) ----
  {
    bf8 aI[2], aIsq[2];
#pragma unroll
    for (int s = 0; s < 2; ++s) {
      int r = i0 + c;
      int sw = (r * 128 + 16 * g + 64 * s) ^ ((r & 7) << 4);
      aI[s]   = *(bf8*)((char*)E16 + sw);
      aIsq[s] = *(bf8*)((char*)E16SQ + sw);
    }
    for (int jt = wv; jt < 7; jt += 4) {
      f32x4 g1 = (f32x4)0.f, g2 = (f32x4)0.f;
#pragma unroll
      for (int s = 0; s < 2; ++s) {
        int r = 16 * jt + c;
        int sw = (r * 128 + 16 * g + 64 * s) ^ ((r & 7) << 4);
        bf8 aj  = *(bf8*)((char*)E16 + sw);
        bf8 ajs = *(bf8*)((char*)E16SQ + sw);
        g1 = __builtin_amdgcn_mfma_f32_16x16x32_bf16(aI[s],   aj,  g1, 0, 0, 0);
        g2 = __builtin_amdgcn_mfma_f32_16x16x32_bf16(aIsq[s], ajs, g2, 0, 0, 0);
      }
      if (g == 0) {
#pragma unroll
        for (int reg = 0; reg < 4; ++reg) {
          float mu  = g1[reg] * (1.f / 64.f);
          float v2  = g2[reg] * (1.f / 64.f);
          float var = v2 - mu * mu;
          float rsv = rsqrtf(var + LN_EPS);
          rs2_s[reg][16 * jt + c]  = C2L * rsv;
          mrs2_s[reg][16 * jt + c] = -C2L * mu * rsv;
        }
      }
    }
  }

  // ---- build B-fragments in registers ----
  bf8 bw3[4][2], bw1[4][2];
  {
    const float* ei = emb + (b * NI + i) * 64;
    float4 eif[4];
#pragma unroll
    for (int s = 0; s < 2; ++s) {
      eif[2*s]   = *(const float4*)(ei + 8 * g + 32 * s);
      eif[2*s+1] = *(const float4*)(ei + 8 * g + 32 * s + 4);
    }
    const float* w3 = ws + OFF_W3GTT;
    const ushort* w1b = (const ushort*)(ws + OFF_W1B);
#pragma unroll
    for (int n = 0; n < 4; ++n) {
      int d = 16 * n + c;
#pragma unroll
      for (int s = 0; s < 2; ++s) {
        const float* wp = w3 + d * 64 + 8 * g + 32 * s;
        float4 w0 = *(const float4*)wp, w1v = *(const float4*)(wp + 4);
        float4 e0 = eif[2*s], e1 = eif[2*s+1];
        int4 pk;
        pk.x = pkt(w0.x * e0.x, w0.y * e0.y);
        pk.y = pkt(w0.z * e0.z, w0.w * e0.w);
        pk.z = pkt(w1v.x * e1.x, w1v.y * e1.y);
        pk.w = pkt(w1v.z * e1.z, w1v.w * e1.w);
        bw3[n][s] = *(bf8*)&pk;
        bw1[n][s] = *(const bf8*)(w1b + (16 * n + c) * 64 + 8 * g + 32 * s);
      }
    }
  }

  // per-lane epilogue constants
  float w3g_n[4], cst2_n[4], wsum_n[4];
#pragma unroll
  for (int n = 0; n < 4; ++n) {
    float t;
    if (wv == 0)      t = apb[n][0];
    else if (wv == 1) t = apb[n][1];
    else if (wv == 2) t = apb[n][2];
    else              t = apb[n][3];
    float pbv = __shfl(t, c, 64);   // broadcast from (g=0, c)
    int d = 16 * n + c;
    w3g_n[n]  = ws[OFF_W3G + d];
    cst2_n[n] = pbv + ws[OFF_C0 + d];
    wsum_n[n] = wsum[d];
  }
  float zbase = ws[OFF_WSUMS] + bsum[0];

  __syncthreads();   // rs2/mrs2 ready

  // ---- pass Q: q3 = E*(e_i o w3g), qa = LNE*w1'; fused epilogue ----
  for (int m = 0; m < 7; ++m) {
    f32x4 q3[4], qa[4];
#pragma unroll
    for (int n = 0; n < 4; ++n) { q3[n] = (f32x4)0.f; qa[n] = (f32x4)0.f; }
#pragma unroll
    for (int s = 0; s < 2; ++s) {
      int r = 16 * m + c;
      int sw = (r * 128 + 16 * g + 64 * s) ^ ((r & 7) << 4);
      bf8 a  = *(bf8*)((char*)E16 + sw);
      bf8 al = *(bf8*)((char*)LNE16 + sw);
#pragma unroll
      for (int n = 0; n < 4; ++n) {
        q3[n] = __builtin_amdgcn_mfma_f32_16x16x32_bf16(a,  bw3[n][s], q3[n], 0, 0, 0);
        qa[n] = __builtin_amdgcn_mfma_f32_16x16x32_bf16(al, bw1[n][s], qa[n], 0, 0, 0);
      }
    }
    float rs2v[4], mrs2v[4];
#pragma unroll
    for (int reg = 0; reg < 4; ++reg) {
      rs2v[reg]  = rs2_s[wv][16 * m + 4 * g + reg];
      mrs2v[reg] = mrs2_s[wv][16 * m + 4 * g + reg];
    }
    float zacc[4] = {0.f, 0.f, 0.f, 0.f};
#pragma unroll
    for (int n = 0; n < 4; ++n) {
#pragma unroll
      for (int reg = 0; reg < 4; ++reg) {
        float X = fmaf(rs2v[reg], q3[n][reg],
                   fmaf(mrs2v[reg], w3g_n[n], qa[n][reg] + cst2_n[n]));
        float ex = exp2f(X);                          // e^{2x}
        float rr = __builtin_amdgcn_rcpf(ex + 1.f);   // tanh = 1 - 2*rr
        zacc[reg] = fmaf(wsum_n[n], rr, zacc[reg]);
      }
    }
#pragma unroll
    for (int reg = 0; reg < 4; ++reg) {
      float zv = zacc[reg];
      zv += __shfl_xor(zv, 1, 64);
      zv += __shfl_xor(zv, 2, 64);
      zv += __shfl_xor(zv, 4, 64);
      zv += __shfl_xor(zv, 8, 64);
      if (c == 0)
        z_s[wv][16 * m + 4 * g + reg] = fmaf(-2.f, zv, zbase);
    }
  }

  // ---- softmax (per wave, own row) ----
  {
    int j0 = lane, j1 = lane + 64;
    bool v0 = (j0 != i);
    bool v1 = (j1 < NI) && (j1 != i);
    float z0 = z_s[wv][j0];
    float z1 = (j1 < NIP) ? z_s[wv][j1] : 0.f;
    z0 = v0 ? z0 : -__builtin_inff();
    z1 = v1 ? z1 : -__builtin_inff();
    float mx = fmaxf(z0, z1);
#pragma unroll
    for (int off = 32; off > 0; off >>= 1)
      mx = fmaxf(mx, __shfl_xor(mx, off, 64));
    float e0 = v0 ? __expf(z0 - mx) : 0.f;
    float e1 = v1 ? __expf(z1 - mx) : 0.f;
    float ss = e0 + e1;
#pragma unroll
    for (int off = 32; off > 0; off >>= 1)
      ss += __shfl_xor(ss, off, 64);
    float inv = 1.f / ss;
    z_s[wv][j0] = e0 * inv;
    if (j1 < NIP) z_s[wv][j1] = e1 * inv;
  }

  // ---- PV + epilogue ----
  {
    int kp = lane & 31, half = lane >> 5;
    float s0 = 0.f, s1 = 0.f;
    int jb = half * 50;
    for (int t = 0; t < 50; ++t) {
      int j = jb + t;
      float al = z_s[wv][j];
      int sw = (j * 128 + kp * 4) ^ ((j & 7) << 4);
      uint32_t u = *(const uint32_t*)((const char*)E16 + sw);
      s0 = fmaf(al, __uint_as_float(u << 16), s0);
      s1 = fmaf(al, __uint_as_float(u & 0xffff0000u), s1);
    }
    s0 += __shfl_xor(s0, 32, 64);
    s1 += __shfl_xor(s1, 32, 64);
    if (half == 0) {
      const float* ei = emb + (b * NI + i) * 64;
      float e0 = ei[2 * kp], e1 = ei[2 * kp + 1];
      float c0 = fmaf(e0, s0, e0 * e0);
      float c1 = fmaf(e1, s1, e1 * e1);
      c0 = (c0 >= 0.f) ? c0 : 0.01f * c0;
      c1 = (c1 >= 0.f) ? c1 : 0.01f * c1;
      float2 o; o.x = c0; o.y = c1;
      *(float2*)(out + (b * NI + i) * 64 + 2 * kp) = o;
    }
  }
}

extern "C" void kernel_launch(void* const* d_in, const int* in_sizes, int n_in,
                              void* d_out, int out_size, void* d_ws, size_t ws_size,
                              hipStream_t stream) {
  const float* emb  = (const float*)d_in[0];
  const float* g    = (const float*)d_in[1];
  const float* bln  = (const float*)d_in[2];
  const float* w_ij = (const float*)d_in[3];
  const float* bij  = (const float*)d_in[4];
  const float* wsum = (const float*)d_in[5];
  const float* bsum = (const float*)d_in[6];
  float* ws  = (float*)d_ws;
  float* out = (float*)d_out;

  hipLaunchKernelGGL(k0_prep, dim3(1), dim3(256), 0, stream,
                     w_ij, g, bln, wsum, bij, ws);
  hipLaunchKernelGGL(k2_main, dim3(BSZ * NT2), dim3(256), 0, stream,
                     emb, g, bln, wsum, bsum, ws, out);
}

// Round 5
// 67.967 us; speedup vs baseline: 1.0010x; 1.0010x over previous
//
#include <hip/hip_runtime.h>
#include <math.h>

#define D 64
#define NI 100
#define BSZ 64
#define LN_EPS 1e-5f
#define NIP 112            // padded j rows (7 tiles of 16)
#define IT 4               // i's per block
#define NT2 25             // i-tiles per batch
#define C2L 2.8853900817779268f   // 2*log2(e)

// ws layout (float indices):
#define OFF_W3GTT 0        // f32 [d][k] = w3[d,k]*g[k]            (4096)
#define OFF_W1B   4096     // bf16 [d][k] = w1[d,k]*C2L            (2048 f32 slots)
#define OFF_W2B   6144     // bf16 [d][k] = w2[d,k]*C2L            (2048)
#define OFF_W3G   8192     // f32 [64] sum_k w3[d,k]*g[k]
#define OFF_C0    8256     // f32 [64] C2L*(bij[d] + sum_k w3[d,k]*bln[k])
#define OFF_WSUMS 8320     // f32 [1] sum(wsum)

typedef __attribute__((ext_vector_type(8))) short bf8;
typedef __attribute__((ext_vector_type(4))) float f32x4;

// rounding f32->bf16
__device__ inline uint32_t f2bf(float x) {
  uint32_t u = __float_as_uint(x);
  return (u + 0x7fffu + ((u >> 16) & 1u)) >> 16;
}
__device__ inline int pk2(float a, float b) { return (int)(f2bf(a) | (f2bf(b) << 16)); }
// truncating pack (3 ops)
__device__ inline int pkt(float a, float b) {
  return (int)((__float_as_uint(a) >> 16) | (__float_as_uint(b) & 0xffff0000u));
}
// square a bf16x8 fragment, truncating round
__device__ inline bf8 sq8t(bf8 a) {
  bf8 r;
#pragma unroll
  for (int t = 0; t < 8; ++t) {
    float v = __uint_as_float(((uint32_t)(unsigned short)a[t]) << 16);
    r[t] = (short)(__float_as_uint(v * v) >> 16);
  }
  return r;
}

// K0: fold/transpose weights once.
__global__ void k0_prep(const float* __restrict__ w_ij,
                        const float* __restrict__ g,
                        const float* __restrict__ bln,
                        const float* __restrict__ wsum,
                        const float* __restrict__ bij,
                        float* __restrict__ ws) {
  __shared__ float w_s[64 * 193];
  int tid = threadIdx.x;
  for (int idx = tid; idx < 64 * 192; idx += 256) {
    int dd = idx / 192, k = idx - dd * 192;
    w_s[dd * 193 + k] = w_ij[idx];
  }
  __syncthreads();
  for (int idx = tid; idx < 4096; idx += 256) {
    int dd = idx >> 6, k = idx & 63;
    ws[OFF_W3GTT + idx] = w_s[dd * 193 + 128 + k] * g[k];
  }
  uint32_t* w1b = (uint32_t*)(ws + OFF_W1B);
  uint32_t* w2b = (uint32_t*)(ws + OFF_W2B);
  for (int idx = tid; idx < 2048; idx += 256) {
    int dd = idx >> 5, kp = (idx & 31) * 2;
    w1b[idx] = pk2(w_s[dd * 193 + kp] * C2L,      w_s[dd * 193 + kp + 1] * C2L);
    w2b[idx] = pk2(w_s[dd * 193 + 64 + kp] * C2L, w_s[dd * 193 + 64 + kp + 1] * C2L);
  }
  if (tid < 64) {
    float wg = 0.f, wb = 0.f;
#pragma unroll
    for (int k = 0; k < 64; ++k) {
      float w = w_s[tid * 193 + 128 + k];
      wg = fmaf(w, g[k], wg);
      wb = fmaf(w, bln[k], wb);
    }
    ws[OFF_W3G + tid] = wg;
    ws[OFF_C0 + tid]  = C2L * (bij[tid] + wb);
  }
  if (tid == 0) {
    float s = 0.f;
    for (int k = 0; k < 64; ++k) s += wsum[k];
    ws[OFF_WSUMS] = s;
  }
}

// K2: one block per (b, 4-i tile); wave wv owns i = i0+wv end-to-end.
// LDS: E16 (bf16 e, whole kernel) + T2 (LNE -> PA overlay) + stats.
__global__ __launch_bounds__(256, 4) void k2_main(
    const float* __restrict__ emb,
    const float* __restrict__ gg,
    const float* __restrict__ bb,
    const float* __restrict__ wsum,
    const float* __restrict__ bsum,
    const float* __restrict__ ws,
    float* __restrict__ out) {
  int bid = blockIdx.x;
  int b = bid / NT2, itile = bid - b * NT2;
  int i0 = itile * IT;
  int tid = threadIdx.x;
  int wv = tid >> 6, lane = tid & 63, g = lane >> 4, c = lane & 15;
  int i = i0 + wv;

  __shared__ ushort E16[NIP * 64];   // 14336 B: bf16 e_j, swizzled
  __shared__ ushort T2[NIP * 64];    // 14336 B: LNE16, then PA (bf16)
  __shared__ float rs2_s[IT][NIP];   // C2L*rs
  __shared__ float mrs2_s[IT][NIP];  // -C2L*mu*rs
  __shared__ float z_s[IT][NIP];     // z then alpha

  const float* eb = emb + b * NI * D;

  // ---- S1: stage e (E16) and LN(e) (T2); 8 threads/row, width-8 shfl stats ----
  for (int u = tid; u < NIP * 8; u += 256) {
    int r = u >> 3, cb = u & 7, kk = cb * 8;
    int4 pe, pl;
    if (r < NI) {
      const float* sp = eb + r * 64 + kk;
      float4 f0 = *(const float4*)sp, f1 = *(const float4*)(sp + 4);
      float s  = f0.x + f0.y + f0.z + f0.w + f1.x + f1.y + f1.z + f1.w;
      float s2 = f0.x*f0.x + f0.y*f0.y + f0.z*f0.z + f0.w*f0.w
               + f1.x*f1.x + f1.y*f1.y + f1.z*f1.z + f1.w*f1.w;
#pragma unroll
      for (int off = 1; off < 8; off <<= 1) {
        s  += __shfl_xor(s, off, 64);
        s2 += __shfl_xor(s2, off, 64);
      }
      float mu  = s * (1.f / 64.f);
      float var = s2 * (1.f / 64.f) - mu * mu;
      float rsv = rsqrtf(var + LN_EPS);
      float4 g0 = *(const float4*)(gg + kk), g1v = *(const float4*)(gg + kk + 4);
      float4 b0 = *(const float4*)(bb + kk), b1v = *(const float4*)(bb + kk + 4);
      float l0 = fmaf((f0.x - mu) * rsv, g0.x, b0.x);
      float l1 = fmaf((f0.y - mu) * rsv, g0.y, b0.y);
      float l2 = fmaf((f0.z - mu) * rsv, g0.z, b0.z);
      float l3 = fmaf((f0.w - mu) * rsv, g0.w, b0.w);
      float l4 = fmaf((f1.x - mu) * rsv, g1v.x, b1v.x);
      float l5 = fmaf((f1.y - mu) * rsv, g1v.y, b1v.y);
      float l6 = fmaf((f1.z - mu) * rsv, g1v.z, b1v.z);
      float l7 = fmaf((f1.w - mu) * rsv, g1v.w, b1v.w);
      pe.x = pkt(f0.x, f0.y); pe.y = pkt(f0.z, f0.w);
      pe.z = pkt(f1.x, f1.y); pe.w = pkt(f1.z, f1.w);
      pl.x = pkt(l0, l1); pl.y = pkt(l2, l3);
      pl.z = pkt(l4, l5); pl.w = pkt(l6, l7);
    } else {
      pe = make_int4(0,0,0,0); pl = pe;
    }
    int sw = (r * 128 + cb * 16) ^ ((r & 7) << 4);
    *(int4*)((char*)E16 + sw) = pe;
    *(int4*)((char*)T2 + sw)  = pl;
  }
  __syncthreads();

  // ---- S2a: Gram stats (squares in-register) ----
  {
    bf8 aI[2], aIsq[2];
#pragma unroll
    for (int s = 0; s < 2; ++s) {
      int r = i0 + c;
      int sw = (r * 128 + 16 * g + 64 * s) ^ ((r & 7) << 4);
      aI[s]   = *(bf8*)((char*)E16 + sw);
      aIsq[s] = sq8t(aI[s]);
    }
    for (int jt = wv; jt < 7; jt += 4) {
      f32x4 g1 = (f32x4)0.f, g2 = (f32x4)0.f;
#pragma unroll
      for (int s = 0; s < 2; ++s) {
        int r = 16 * jt + c;
        int sw = (r * 128 + 16 * g + 64 * s) ^ ((c & 7) << 4);
        bf8 aj  = *(bf8*)((char*)E16 + sw);
        bf8 ajs = sq8t(aj);
        g1 = __builtin_amdgcn_mfma_f32_16x16x32_bf16(aI[s],   aj,  g1, 0, 0, 0);
        g2 = __builtin_amdgcn_mfma_f32_16x16x32_bf16(aIsq[s], ajs, g2, 0, 0, 0);
      }
      if (g == 0) {
#pragma unroll
        for (int reg = 0; reg < 4; ++reg) {
          float mu  = g1[reg] * (1.f / 64.f);
          float v2  = g2[reg] * (1.f / 64.f);
          float var = v2 - mu * mu;
          float rsv = rsqrtf(var + LN_EPS);
          rs2_s[reg][16 * jt + c]  = C2L * rsv;
          mrs2_s[reg][16 * jt + c] = -C2L * mu * rsv;
        }
      }
    }
  }

  // ---- S2b: all LNE reads (pb frags, PA A-frags) + pb MFMA ----
  f32x4 apb[4];
#pragma unroll
  for (int n = 0; n < 4; ++n) apb[n] = (f32x4)0.f;
  {
    bf8 alI[2];
#pragma unroll
    for (int s = 0; s < 2; ++s) {
      int r = i0 + c;
      int sw = (r * 128 + 16 * g + 64 * s) ^ ((r & 7) << 4);
      alI[s] = *(bf8*)((char*)T2 + sw);
    }
    const ushort* w2b = (const ushort*)(ws + OFF_W2B);
#pragma unroll
    for (int s = 0; s < 2; ++s)
#pragma unroll
      for (int n = 0; n < 4; ++n) {
        bf8 b2 = *(const bf8*)(w2b + (16 * n + c) * 64 + 8 * g + 32 * s);
        apb[n] = __builtin_amdgcn_mfma_f32_16x16x32_bf16(alI[s], b2, apb[n], 0, 0, 0);
      }
  }
  int m0 = wv, m1 = wv + 4;
  bool has1 = (m1 < 7);
  bf8 paA0[2], paA1[2];
#pragma unroll
  for (int s = 0; s < 2; ++s) {
    int r0 = 16 * m0 + c;
    paA0[s] = *(bf8*)((char*)T2 + ((r0 * 128 + 16 * g + 64 * s) ^ ((c & 7) << 4)));
  }
  if (has1) {
#pragma unroll
    for (int s = 0; s < 2; ++s) {
      int r1 = 16 * m1 + c;
      paA1[s] = *(bf8*)((char*)T2 + ((r1 * 128 + 16 * g + 64 * s) ^ ((c & 7) << 4)));
    }
  }
  bf8 bw1[4][2];
  {
    const ushort* w1b = (const ushort*)(ws + OFF_W1B);
#pragma unroll
    for (int n = 0; n < 4; ++n)
#pragma unroll
      for (int s = 0; s < 2; ++s)
        bw1[n][s] = *(const bf8*)(w1b + (16 * n + c) * 64 + 8 * g + 32 * s);
  }
  __syncthreads();   // all LNE reads complete

  // ---- S3: PA GEMM -> overwrite T2 with PA (bf16) ----
  {
    int swz = ((4 * g) & 7) << 4;  // row-dependent part added per reg below
#pragma unroll
    for (int t = 0; t < 2; ++t) {
      if (t == 1 && !has1) break;
      int mt = (t == 0) ? m0 : m1;
      f32x4 acc[4];
#pragma unroll
      for (int n = 0; n < 4; ++n) acc[n] = (f32x4)0.f;
#pragma unroll
      for (int s = 0; s < 2; ++s) {
        bf8 a = (t == 0) ? paA0[s] : paA1[s];
#pragma unroll
        for (int n = 0; n < 4; ++n)
          acc[n] = __builtin_amdgcn_mfma_f32_16x16x32_bf16(a, bw1[n][s], acc[n], 0, 0, 0);
      }
#pragma unroll
      for (int n = 0; n < 4; ++n)
#pragma unroll
        for (int reg = 0; reg < 4; ++reg) {
          float val = acc[n][reg];
          float o = __shfl_xor(val, 1, 64);
          if ((c & 1) == 0) {
            int j = 16 * mt + 4 * g + reg;
            int byte = (j * 128 + 2 * (16 * n + c)) ^ (((4 * g + reg) & 7) << 4);
            *(uint32_t*)((char*)T2 + byte) = pk2(val, o);
          }
        }
    }
    (void)swz;
  }

  // ---- bw3 fragments (e_i o w3g) in registers ----
  bf8 bw3[4][2];
  {
    const float* ei = emb + (b * NI + i) * 64;
    float4 eif[4];
#pragma unroll
    for (int s = 0; s < 2; ++s) {
      eif[2*s]   = *(const float4*)(ei + 8 * g + 32 * s);
      eif[2*s+1] = *(const float4*)(ei + 8 * g + 32 * s + 4);
    }
    const float* w3 = ws + OFF_W3GTT;
#pragma unroll
    for (int n = 0; n < 4; ++n) {
      int d = 16 * n + c;
#pragma unroll
      for (int s = 0; s < 2; ++s) {
        const float* wp = w3 + d * 64 + 8 * g + 32 * s;
        float4 w0 = *(const float4*)wp, w1v = *(const float4*)(wp + 4);
        float4 e0 = eif[2*s], e1 = eif[2*s+1];
        int4 pk;
        pk.x = pkt(w0.x * e0.x, w0.y * e0.y);
        pk.y = pkt(w0.z * e0.z, w0.w * e0.w);
        pk.z = pkt(w1v.x * e1.x, w1v.y * e1.y);
        pk.w = pkt(w1v.z * e1.z, w1v.w * e1.w);
        bw3[n][s] = *(bf8*)&pk;
      }
    }
  }

  // per-lane epilogue constants
  float w3g_n[4], cst2_n[4], wsum_n[4];
#pragma unroll
  for (int n = 0; n < 4; ++n) {
    float t;
    if (wv == 0)      t = apb[n][0];
    else if (wv == 1) t = apb[n][1];
    else if (wv == 2) t = apb[n][2];
    else              t = apb[n][3];
    float pbv = __shfl(t, c, 64);   // broadcast from (g=0, c)
    int d = 16 * n + c;
    w3g_n[n]  = ws[OFF_W3G + d];
    cst2_n[n] = pbv + ws[OFF_C0 + d];
    wsum_n[n] = wsum[d];
  }
  float zbase = ws[OFF_WSUMS] + bsum[0];

  __syncthreads();   // PA ready

  // ---- S4 pass Q: q3 = E*(e_i o w3g); epilogue reads PA from T2 ----
  for (int m = 0; m < 7; ++m) {
    f32x4 q3[4];
#pragma unroll
    for (int n = 0; n < 4; ++n) q3[n] = (f32x4)0.f;
#pragma unroll
    for (int s = 0; s < 2; ++s) {
      int r = 16 * m + c;
      int sw = (r * 128 + 16 * g + 64 * s) ^ ((c & 7) << 4);
      bf8 a = *(bf8*)((char*)E16 + sw);
#pragma unroll
      for (int n = 0; n < 4; ++n)
        q3[n] = __builtin_amdgcn_mfma_f32_16x16x32_bf16(a, bw3[n][s], q3[n], 0, 0, 0);
    }
    float rs2v[4], mrs2v[4];
#pragma unroll
    for (int reg = 0; reg < 4; ++reg) {
      rs2v[reg]  = rs2_s[wv][16 * m + 4 * g + reg];
      mrs2v[reg] = mrs2_s[wv][16 * m + 4 * g + reg];
    }
    float zacc[4] = {0.f, 0.f, 0.f, 0.f};
#pragma unroll
    for (int n = 0; n < 4; ++n) {
#pragma unroll
      for (int reg = 0; reg < 4; ++reg) {
        int j = 16 * m + 4 * g + reg;
        ushort pu = *(const ushort*)((const char*)T2 +
            ((j * 128 + 2 * (16 * n + c)) ^ (((4 * g + reg) & 7) << 4)));
        float paf = __uint_as_float(((uint32_t)pu) << 16);
        float X = fmaf(rs2v[reg], q3[n][reg],
                   fmaf(mrs2v[reg], w3g_n[n], paf + cst2_n[n]));
        float ex = exp2f(X);                          // e^{2x}
        float rr = __builtin_amdgcn_rcpf(ex + 1.f);   // tanh = 1 - 2*rr
        zacc[reg] = fmaf(wsum_n[n], rr, zacc[reg]);
      }
    }
#pragma unroll
    for (int reg = 0; reg < 4; ++reg) {
      float zv = zacc[reg];
      zv += __shfl_xor(zv, 1, 64);
      zv += __shfl_xor(zv, 2, 64);
      zv += __shfl_xor(zv, 4, 64);
      zv += __shfl_xor(zv, 8, 64);
      if (c == 0)
        z_s[wv][16 * m + 4 * g + reg] = fmaf(-2.f, zv, zbase);
    }
  }

  // ---- softmax (per wave, own row) ----
  {
    int j0 = lane, j1 = lane + 64;
    bool v0 = (j0 != i);
    bool v1 = (j1 < NI) && (j1 != i);
    float z0 = z_s[wv][j0];
    float z1 = (j1 < NIP) ? z_s[wv][j1] : 0.f;
    z0 = v0 ? z0 : -__builtin_inff();
    z1 = v1 ? z1 : -__builtin_inff();
    float mx = fmaxf(z0, z1);
#pragma unroll
    for (int off = 32; off > 0; off >>= 1)
      mx = fmaxf(mx, __shfl_xor(mx, off, 64));
    float e0 = v0 ? __expf(z0 - mx) : 0.f;
    float e1 = v1 ? __expf(z1 - mx) : 0.f;
    float ss = e0 + e1;
#pragma unroll
    for (int off = 32; off > 0; off >>= 1)
      ss += __shfl_xor(ss, off, 64);
    float inv = 1.f / ss;
    z_s[wv][j0] = e0 * inv;
    if (j1 < NIP) z_s[wv][j1] = e1 * inv;
  }

  // ---- PV + epilogue ----
  {
    int kp = lane & 31, half = lane >> 5;
    float s0 = 0.f, s1 = 0.f;
    int jb = half * 50;
    for (int t = 0; t < 50; ++t) {
      int j = jb + t;
      float al = z_s[wv][j];
      int sw = (j * 128 + kp * 4) ^ ((j & 7) << 4);
      uint32_t u = *(const uint32_t*)((const char*)E16 + sw);
      s0 = fmaf(al, __uint_as_float(u << 16), s0);
      s1 = fmaf(al, __uint_as_float(u & 0xffff0000u), s1);
    }
    s0 += __shfl_xor(s0, 32, 64);
    s1 += __shfl_xor(s1, 32, 64);
    if (half == 0) {
      const float* ei = emb + (b * NI + i) * 64;
      float e0 = ei[2 * kp], e1 = ei[2 * kp + 1];
      float c0 = fmaf(e0, s0, e0 * e0);
      float c1 = fmaf(e1, s1, e1 * e1);
      c0 = (c0 >= 0.f) ? c0 : 0.01f * c0;
      c1 = (c1 >= 0.f) ? c1 : 0.01f * c1;
      float2 o; o.x = c0; o.y = c1;
      *(float2*)(out + (b * NI + i) * 64 + 2 * kp) = o;
    }
  }
}

extern "C" void kernel_launch(void* const* d_in, const int* in_sizes, int n_in,
                              void* d_out, int out_size, void* d_ws, size_t ws_size,
                              hipStream_t stream) {
  const float* emb  = (const float*)d_in[0];
  const float* g    = (const float*)d_in[1];
  const float* bln  = (const float*)d_in[2];
  const float* w_ij = (const float*)d_in[3];
  const float* bij  = (const float*)d_in[4];
  const float* wsum = (const float*)d_in[5];
  const float* bsum = (const float*)d_in[6];
  float* ws  = (float*)d_ws;
  float* out = (float*)d_out;

  hipLaunchKernelGGL(k0_prep, dim3(1), dim3(256), 0, stream,
                     w_ij, g, bln, wsum, bij, ws);
  hipLaunchKernelGGL(k2_main, dim3(BSZ * NT2), dim3(256), 0, stream,
                     emb, g, bln, wsum, bsum, ws, out);
}

// Round 6
// 64.944 us; speedup vs baseline: 1.0476x; 1.0465x over previous
//
#include <hip/hip_runtime.h>
#include <math.h>

#define D 64
#define NI 100
#define BSZ 64
#define LN_EPS 1e-5f
#define NIP 112            // padded j rows (7 tiles of 16)
#define IT 4               // i's per block
#define NT2 25             // i-tiles per batch
#define C2L 2.8853900817779268f   // 2*log2(e)
#define TILEB 14336        // bytes per per-batch bf16 tile (NIP*64*2)

// ws layout (float indices):
#define OFF_W3GTT 0        // f32 [d][k] = w3[d,k]*g[k]            (4096)
#define OFF_W1B   4096     // bf16 [d][k] = w1[d,k]*C2L            (2048 f32 slots)
#define OFF_W2B   6144     // bf16 [d][k] = w2[d,k]*C2L            (2048)
#define OFF_W3G   8192     // f32 [64] sum_k w3[d,k]*g[k]
#define OFF_C0    8256     // f32 [64] C2L*(bij[d] + sum_k w3[d,k]*bln[k])
#define OFF_WSUMS 8320     // f32 [1] sum(wsum)
#define OFF_PB16  8448     // bf16 [6400*64] = C2L * LN(e_t).w2    (204800 f32 slots)
#define OFF_E16   213248   // 64 x TILEB: bf16 e, swizzled         (229376)
#define OFF_E2    442624   // 64 x TILEB: bf16 e^2, swizzled       (229376)
#define OFF_PA16  672000   // 64 x TILEB: bf16 PA [j][c][n]        (229376)

typedef __attribute__((ext_vector_type(8))) short bf8;
typedef __attribute__((ext_vector_type(4))) float f32x4;

// rounding f32->bf16
__device__ inline uint32_t f2bf(float x) {
  uint32_t u = __float_as_uint(x);
  return (u + 0x7fffu + ((u >> 16) & 1u)) >> 16;
}
__device__ inline int pk2(float a, float b) { return (int)(f2bf(a) | (f2bf(b) << 16)); }
// truncating pack (3 ops)
__device__ inline int pkt(float a, float b) {
  return (int)((__float_as_uint(a) >> 16) | (__float_as_uint(b) & 0xffff0000u));
}

// K0: fold/transpose weights once.
__global__ void k0_prep(const float* __restrict__ w_ij,
                        const float* __restrict__ g,
                        const float* __restrict__ bln,
                        const float* __restrict__ wsum,
                        const float* __restrict__ bij,
                        float* __restrict__ ws) {
  __shared__ float w_s[64 * 193];
  int tid = threadIdx.x;
  for (int idx = tid; idx < 64 * 192; idx += 256) {
    int dd = idx / 192, k = idx - dd * 192;
    w_s[dd * 193 + k] = w_ij[idx];
  }
  __syncthreads();
  for (int idx = tid; idx < 4096; idx += 256) {
    int dd = idx >> 6, k = idx & 63;
    ws[OFF_W3GTT + idx] = w_s[dd * 193 + 128 + k] * g[k];
  }
  uint32_t* w1b = (uint32_t*)(ws + OFF_W1B);
  uint32_t* w2b = (uint32_t*)(ws + OFF_W2B);
  for (int idx = tid; idx < 2048; idx += 256) {
    int dd = idx >> 5, kp = (idx & 31) * 2;
    w1b[idx] = pk2(w_s[dd * 193 + kp] * C2L,      w_s[dd * 193 + kp + 1] * C2L);
    w2b[idx] = pk2(w_s[dd * 193 + 64 + kp] * C2L, w_s[dd * 193 + 64 + kp + 1] * C2L);
  }
  if (tid < 64) {
    float wg = 0.f, wb = 0.f;
#pragma unroll
    for (int k = 0; k < 64; ++k) {
      float w = w_s[tid * 193 + 128 + k];
      wg = fmaf(w, g[k], wg);
      wb = fmaf(w, bln[k], wb);
    }
    ws[OFF_W3G + tid] = wg;
    ws[OFF_C0 + tid]  = C2L * (bij[tid] + wb);
  }
  if (tid == 0) {
    float s = 0.f;
    for (int k = 0; k < 64; ++k) s += wsum[k];
    ws[OFF_WSUMS] = s;
  }
}

// K1: one block per batch b. Stage+LN once; emit E16/E16SQ tiles (swizzled bf16),
// PA16 = C2L*LNE.w1 (bf16, [j][c][n] b64-packed), PB16 = C2L*LNE.w2 (bf16 [t][d]).
__global__ __launch_bounds__(256) void k1_batch(
    const float* __restrict__ emb,
    const float* __restrict__ gg,
    const float* __restrict__ bb,
    float* __restrict__ ws) {
  int b = blockIdx.x;
  int tid = threadIdx.x;
  int wv = tid >> 6, lane = tid & 63, g = lane >> 4, c = lane & 15;

  __shared__ ushort LNE16[NIP * 64];   // 14336 B, swizzled
  char* e16g  = (char*)ws + OFF_E16  * 4 + b * TILEB;
  char* e2g   = (char*)ws + OFF_E2   * 4 + b * TILEB;
  char* pa16g = (char*)ws + OFF_PA16 * 4 + b * TILEB;
  ushort* pb16 = (ushort*)(ws + OFF_PB16);
  const float* eb = emb + b * NI * D;

  // stage: e -> E16(global), e^2 -> E2(global), LN(e) -> LNE16(LDS)
  for (int u = tid; u < NIP * 8; u += 256) {
    int r = u >> 3, cb = u & 7, kk = cb * 8;
    int4 pe, ps, pl;
    if (r < NI) {
      const float* sp = eb + r * 64 + kk;
      float4 f0 = *(const float4*)sp, f1 = *(const float4*)(sp + 4);
      float s  = f0.x + f0.y + f0.z + f0.w + f1.x + f1.y + f1.z + f1.w;
      float s2 = f0.x*f0.x + f0.y*f0.y + f0.z*f0.z + f0.w*f0.w
               + f1.x*f1.x + f1.y*f1.y + f1.z*f1.z + f1.w*f1.w;
#pragma unroll
      for (int off = 1; off < 8; off <<= 1) {
        s  += __shfl_xor(s, off, 64);
        s2 += __shfl_xor(s2, off, 64);
      }
      float mu  = s * (1.f / 64.f);
      float var = s2 * (1.f / 64.f) - mu * mu;
      float rsv = rsqrtf(var + LN_EPS);
      float4 g0 = *(const float4*)(gg + kk), g1v = *(const float4*)(gg + kk + 4);
      float4 b0 = *(const float4*)(bb + kk), b1v = *(const float4*)(bb + kk + 4);
      float l0 = fmaf((f0.x - mu) * rsv, g0.x, b0.x);
      float l1 = fmaf((f0.y - mu) * rsv, g0.y, b0.y);
      float l2 = fmaf((f0.z - mu) * rsv, g0.z, b0.z);
      float l3 = fmaf((f0.w - mu) * rsv, g0.w, b0.w);
      float l4 = fmaf((f1.x - mu) * rsv, g1v.x, b1v.x);
      float l5 = fmaf((f1.y - mu) * rsv, g1v.y, b1v.y);
      float l6 = fmaf((f1.z - mu) * rsv, g1v.z, b1v.z);
      float l7 = fmaf((f1.w - mu) * rsv, g1v.w, b1v.w);
      pe.x = pkt(f0.x, f0.y); pe.y = pkt(f0.z, f0.w);
      pe.z = pkt(f1.x, f1.y); pe.w = pkt(f1.z, f1.w);
      ps.x = pkt(f0.x*f0.x, f0.y*f0.y); ps.y = pkt(f0.z*f0.z, f0.w*f0.w);
      ps.z = pkt(f1.x*f1.x, f1.y*f1.y); ps.w = pkt(f1.z*f1.z, f1.w*f1.w);
      pl.x = pkt(l0, l1); pl.y = pkt(l2, l3);
      pl.z = pkt(l4, l5); pl.w = pkt(l6, l7);
    } else {
      pe = make_int4(0,0,0,0); ps = pe; pl = pe;
    }
    int sw = (r * 128 + cb * 16) ^ ((r & 7) << 4);
    *(int4*)(e16g + sw) = pe;
    *(int4*)(e2g + sw)  = ps;
    *(int4*)((char*)LNE16 + sw) = pl;
  }
  __syncthreads();

  // B-fragments
  bf8 bw1[4][2], bw2[4][2];
  {
    const ushort* w1b = (const ushort*)(ws + OFF_W1B);
    const ushort* w2b = (const ushort*)(ws + OFF_W2B);
#pragma unroll
    for (int n = 0; n < 4; ++n)
#pragma unroll
      for (int s = 0; s < 2; ++s) {
        bw1[n][s] = *(const bf8*)(w1b + (16 * n + c) * 64 + 8 * g + 32 * s);
        bw2[n][s] = *(const bf8*)(w2b + (16 * n + c) * 64 + 8 * g + 32 * s);
      }
  }

  // PA/PB GEMM over m-tiles (wave wv owns m = wv, wv+4)
  for (int m = wv; m < 7; m += 4) {
    bf8 a[2];
#pragma unroll
    for (int s = 0; s < 2; ++s) {
      int r = 16 * m + c;
      a[s] = *(bf8*)((char*)LNE16 + ((r * 128 + 16 * g + 64 * s) ^ ((r & 7) << 4)));
    }
    f32x4 pa[4], pbk[4];
#pragma unroll
    for (int n = 0; n < 4; ++n) { pa[n] = (f32x4)0.f; pbk[n] = (f32x4)0.f; }
#pragma unroll
    for (int s = 0; s < 2; ++s)
#pragma unroll
      for (int n = 0; n < 4; ++n) {
        pa[n]  = __builtin_amdgcn_mfma_f32_16x16x32_bf16(a[s], bw1[n][s], pa[n], 0, 0, 0);
        pbk[n] = __builtin_amdgcn_mfma_f32_16x16x32_bf16(a[s], bw2[n][s], pbk[n], 0, 0, 0);
      }
#pragma unroll
    for (int reg = 0; reg < 4; ++reg) {
      int j = 16 * m + 4 * g + reg;
      uint2 v;
      v.x = (uint32_t)pk2(pa[0][reg], pa[1][reg]);
      v.y = (uint32_t)pk2(pa[2][reg], pa[3][reg]);
      *(uint2*)(pa16g + j * 128 + c * 8) = v;     // [j][c][n], no swizzle
      if (j < NI) {
#pragma unroll
        for (int n = 0; n < 4; ++n)
          pb16[(b * NI + j) * 64 + 16 * n + c] = (ushort)f2bf(pbk[n][reg]);
      }
    }
  }
}

// K2: one block per (b, 4-i tile); wave wv owns i = i0+wv end-to-end.
__global__ __launch_bounds__(256, 4) void k2_main(
    const float* __restrict__ emb,
    const float* __restrict__ wsum,
    const float* __restrict__ bsum,
    const float* __restrict__ ws,
    float* __restrict__ out) {
  int bid = blockIdx.x;
  int b = bid / NT2, itile = bid - b * NT2;
  int i0 = itile * IT;
  int tid = threadIdx.x;
  int wv = tid >> 6, lane = tid & 63, g = lane >> 4, c = lane & 15;
  int i = i0 + wv;

  __shared__ ushort E16[NIP * 64];   // 14336 B: bf16 e_j, swizzled
  __shared__ float rs2_s[IT][NIP];   // C2L*rs
  __shared__ float mrs2_s[IT][NIP];  // -C2L*mu*rs
  __shared__ float z_s[IT][NIP];     // z then alpha

  const char* e16g  = (const char*)ws + OFF_E16  * 4 + b * TILEB;
  const char* e2g   = (const char*)ws + OFF_E2   * 4 + b * TILEB;
  const char* pa16g = (const char*)ws + OFF_PA16 * 4 + b * TILEB;
  const ushort* pb16 = (const ushort*)(ws + OFF_PB16);

  // stage E16 (linear copy; swizzle baked in)
  for (int u = tid; u < TILEB / 16; u += 256)
    ((int4*)E16)[u] = ((const int4*)e16g)[u];
  __syncthreads();

  // ---- Gram stats (squares from global E2 tile) ----
  {
    bf8 aI[2], aIsq[2];
#pragma unroll
    for (int s = 0; s < 2; ++s) {
      int r = i0 + c;
      int sw = (r * 128 + 16 * g + 64 * s) ^ ((r & 7) << 4);
      aI[s]   = *(bf8*)((char*)E16 + sw);
      aIsq[s] = *(const bf8*)(e2g + sw);
    }
    for (int jt = wv; jt < 7; jt += 4) {
      f32x4 g1 = (f32x4)0.f, g2 = (f32x4)0.f;
#pragma unroll
      for (int s = 0; s < 2; ++s) {
        int r = 16 * jt + c;
        int sw = (r * 128 + 16 * g + 64 * s) ^ ((r & 7) << 4);
        bf8 aj  = *(bf8*)((char*)E16 + sw);
        bf8 ajs = *(const bf8*)(e2g + sw);
        g1 = __builtin_amdgcn_mfma_f32_16x16x32_bf16(aI[s],   aj,  g1, 0, 0, 0);
        g2 = __builtin_amdgcn_mfma_f32_16x16x32_bf16(aIsq[s], ajs, g2, 0, 0, 0);
      }
      if (g == 0) {
#pragma unroll
        for (int reg = 0; reg < 4; ++reg) {
          float mu  = g1[reg] * (1.f / 64.f);
          float v2  = g2[reg] * (1.f / 64.f);
          float var = v2 - mu * mu;
          float rsv = rsqrtf(var + LN_EPS);
          rs2_s[reg][16 * jt + c]  = C2L * rsv;
          mrs2_s[reg][16 * jt + c] = -C2L * mu * rsv;
        }
      }
    }
  }

  // ---- bw3 fragments (e_i o w3g) in registers ----
  bf8 bw3[4][2];
  {
    const float* ei = emb + (b * NI + i) * 64;
    float4 eif[4];
#pragma unroll
    for (int s = 0; s < 2; ++s) {
      eif[2*s]   = *(const float4*)(ei + 8 * g + 32 * s);
      eif[2*s+1] = *(const float4*)(ei + 8 * g + 32 * s + 4);
    }
    const float* w3 = ws + OFF_W3GTT;
#pragma unroll
    for (int n = 0; n < 4; ++n) {
      int d = 16 * n + c;
#pragma unroll
      for (int s = 0; s < 2; ++s) {
        const float* wp = w3 + d * 64 + 8 * g + 32 * s;
        float4 w0 = *(const float4*)wp, w1v = *(const float4*)(wp + 4);
        float4 e0 = eif[2*s], e1 = eif[2*s+1];
        int4 pk;
        pk.x = pkt(w0.x * e0.x, w0.y * e0.y);
        pk.y = pkt(w0.z * e0.z, w0.w * e0.w);
        pk.z = pkt(w1v.x * e1.x, w1v.y * e1.y);
        pk.w = pkt(w1v.z * e1.z, w1v.w * e1.w);
        bw3[n][s] = *(bf8*)&pk;
      }
    }
  }

  // per-lane epilogue constants
  float w3g_n[4], cst2_n[4], wsum_n[4];
#pragma unroll
  for (int n = 0; n < 4; ++n) {
    int d = 16 * n + c;
    float pbv = __uint_as_float(((uint32_t)pb16[(b * NI + i) * 64 + d]) << 16);
    w3g_n[n]  = ws[OFF_W3G + d];
    cst2_n[n] = pbv + ws[OFF_C0 + d];
    wsum_n[n] = wsum[d];
  }
  float zbase = ws[OFF_WSUMS] + bsum[0];

  __syncthreads();   // rs2/mrs2 ready

  // ---- pass Q: q3 = E*(e_i o w3g); PA from global b64; fused epilogue ----
  for (int m = 0; m < 7; ++m) {
    uint2 pav[4];
#pragma unroll
    for (int reg = 0; reg < 4; ++reg) {
      int j = 16 * m + 4 * g + reg;
      pav[reg] = *(const uint2*)(pa16g + j * 128 + c * 8);
    }
    f32x4 q3[4];
#pragma unroll
    for (int n = 0; n < 4; ++n) q3[n] = (f32x4)0.f;
#pragma unroll
    for (int s = 0; s < 2; ++s) {
      int r = 16 * m + c;
      int sw = (r * 128 + 16 * g + 64 * s) ^ ((r & 7) << 4);
      bf8 a = *(bf8*)((char*)E16 + sw);
#pragma unroll
      for (int n = 0; n < 4; ++n)
        q3[n] = __builtin_amdgcn_mfma_f32_16x16x32_bf16(a, bw3[n][s], q3[n], 0, 0, 0);
    }
    float rs2v[4], mrs2v[4];
#pragma unroll
    for (int reg = 0; reg < 4; ++reg) {
      rs2v[reg]  = rs2_s[wv][16 * m + 4 * g + reg];
      mrs2v[reg] = mrs2_s[wv][16 * m + 4 * g + reg];
    }
    float zacc[4] = {0.f, 0.f, 0.f, 0.f};
#pragma unroll
    for (int reg = 0; reg < 4; ++reg) {
      float paf[4];
      paf[0] = __uint_as_float(pav[reg].x << 16);
      paf[1] = __uint_as_float(pav[reg].x & 0xffff0000u);
      paf[2] = __uint_as_float(pav[reg].y << 16);
      paf[3] = __uint_as_float(pav[reg].y & 0xffff0000u);
#pragma unroll
      for (int n = 0; n < 4; ++n) {
        float X = fmaf(rs2v[reg], q3[n][reg],
                   fmaf(mrs2v[reg], w3g_n[n], paf[n] + cst2_n[n]));
        float ex = exp2f(X);                          // e^{2x}
        float rr = __builtin_amdgcn_rcpf(ex + 1.f);   // tanh = 1 - 2*rr
        zacc[reg] = fmaf(wsum_n[n], rr, zacc[reg]);
      }
    }
#pragma unroll
    for (int reg = 0; reg < 4; ++reg) {
      float zv = zacc[reg];
      zv += __shfl_xor(zv, 1, 64);
      zv += __shfl_xor(zv, 2, 64);
      zv += __shfl_xor(zv, 4, 64);
      zv += __shfl_xor(zv, 8, 64);
      if (c == 0)
        z_s[wv][16 * m + 4 * g + reg] = fmaf(-2.f, zv, zbase);
    }
  }

  // ---- softmax (per wave, own row) ----
  {
    int j0 = lane, j1 = lane + 64;
    bool v0 = (j0 != i);
    bool v1 = (j1 < NI) && (j1 != i);
    float z0 = z_s[wv][j0];
    float z1 = (j1 < NIP) ? z_s[wv][j1] : 0.f;
    z0 = v0 ? z0 : -__builtin_inff();
    z1 = v1 ? z1 : -__builtin_inff();
    float mx = fmaxf(z0, z1);
#pragma unroll
    for (int off = 32; off > 0; off >>= 1)
      mx = fmaxf(mx, __shfl_xor(mx, off, 64));
    float e0 = v0 ? __expf(z0 - mx) : 0.f;
    float e1 = v1 ? __expf(z1 - mx) : 0.f;
    float ss = e0 + e1;
#pragma unroll
    for (int off = 32; off > 0; off >>= 1)
      ss += __shfl_xor(ss, off, 64);
    float inv = 1.f / ss;
    z_s[wv][j0] = e0 * inv;
    if (j1 < NIP) z_s[wv][j1] = e1 * inv;
  }

  // ---- PV + epilogue ----
  {
    int kp = lane & 31, half = lane >> 5;
    float s0 = 0.f, s1 = 0.f;
    int jb = half * 50;
    for (int t = 0; t < 50; ++t) {
      int j = jb + t;
      float al = z_s[wv][j];
      int sw = (j * 128 + kp * 4) ^ ((j & 7) << 4);
      uint32_t u = *(const uint32_t*)((const char*)E16 + sw);
      s0 = fmaf(al, __uint_as_float(u << 16), s0);
      s1 = fmaf(al, __uint_as_float(u & 0xffff0000u), s1);
    }
    s0 += __shfl_xor(s0, 32, 64);
    s1 += __shfl_xor(s1, 32, 64);
    if (half == 0) {
      const float* ei = emb + (b * NI + i) * 64;
      float e0 = ei[2 * kp], e1 = ei[2 * kp + 1];
      float c0 = fmaf(e0, s0, e0 * e0);
      float c1 = fmaf(e1, s1, e1 * e1);
      c0 = (c0 >= 0.f) ? c0 : 0.01f * c0;
      c1 = (c1 >= 0.f) ? c1 : 0.01f * c1;
      float2 o; o.x = c0; o.y = c1;
      *(float2*)(out + (b * NI + i) * 64 + 2 * kp) = o;
    }
  }
}

extern "C" void kernel_launch(void* const* d_in, const int* in_sizes, int n_in,
                              void* d_out, int out_size, void* d_ws, size_t ws_size,
                              hipStream_t stream) {
  const float* emb  = (const float*)d_in[0];
  const float* g    = (const float*)d_in[1];
  const float* bln  = (const float*)d_in[2];
  const float* w_ij = (const float*)d_in[3];
  const float* bij  = (const float*)d_in[4];
  const float* wsum = (const float*)d_in[5];
  const float* bsum = (const float*)d_in[6];
  float* ws  = (float*)d_ws;
  float* out = (float*)d_out;

  hipLaunchKernelGGL(k0_prep, dim3(1), dim3(256), 0, stream,
                     w_ij, g, bln, wsum, bij, ws);
  hipLaunchKernelGGL(k1_batch, dim3(BSZ), dim3(256), 0, stream,
                     emb, g, bln, ws);
  hipLaunchKernelGGL(k2_main, dim3(BSZ * NT2), dim3(256), 0, stream,
                     emb, wsum, bsum, ws, out);
}

// Round 7
// 61.297 us; speedup vs baseline: 1.1099x; 1.0595x over previous
//
#include <hip/hip_runtime.h>
#include <math.h>

#define D 64
#define NI 100
#define BSZ 64
#define LN_EPS 1e-5f
#define NIP 112            // padded j rows (7 tiles of 16)
#define IT 4               // i's per block
#define NT2 25             // i-tiles per batch
#define C2L 2.8853900817779268f   // 2*log2(e)
#define TILEB 14336        // bytes per per-batch bf16 tile (NIP*64*2)

// ws layout (float indices):
#define OFF_W3GTT 0        // f32 [d][k] = w3[d,k]*g[k]            (4096)
#define OFF_W1B   4096     // bf16 [d][k] = w1[d,k]*C2L            (2048 f32 slots)
#define OFF_W2B   6144     // bf16 [d][k] = w2[d,k]*C2L            (2048)
#define OFF_W3G   8192     // f32 [64] sum_k w3[d,k]*g[k]
#define OFF_C0    8256     // f32 [64] C2L*(bij[d] + sum_k w3[d,k]*bln[k])
#define OFF_WSUMS 8320     // f32 [1] sum(wsum)
#define OFF_PB16  8448     // bf16 [6400*64] = C2L * LN(e_t).w2    (204800 f32 slots)
#define OFF_E16   213248   // 64 x TILEB: bf16 e, swizzled         (229376)
#define OFF_E2    442624   // 64 x TILEB: bf16 e^2, swizzled       (229376)
#define OFF_PA16  672000   // 64 x TILEB: bf16 PA [j][c][n]        (229376)

typedef __attribute__((ext_vector_type(8))) short bf8;
typedef __attribute__((ext_vector_type(4))) float f32x4;

// rounding f32->bf16
__device__ inline uint32_t f2bf(float x) {
  uint32_t u = __float_as_uint(x);
  return (u + 0x7fffu + ((u >> 16) & 1u)) >> 16;
}
__device__ inline int pk2(float a, float b) { return (int)(f2bf(a) | (f2bf(b) << 16)); }
// truncating pack (3 ops)
__device__ inline int pkt(float a, float b) {
  return (int)((__float_as_uint(a) >> 16) | (__float_as_uint(b) & 0xffff0000u));
}

// K0: fold/transpose weights once.
__global__ void k0_prep(const float* __restrict__ w_ij,
                        const float* __restrict__ g,
                        const float* __restrict__ bln,
                        const float* __restrict__ wsum,
                        const float* __restrict__ bij,
                        float* __restrict__ ws) {
  __shared__ float w_s[64 * 193];
  int tid = threadIdx.x;
  for (int idx = tid; idx < 64 * 192; idx += 256) {
    int dd = idx / 192, k = idx - dd * 192;
    w_s[dd * 193 + k] = w_ij[idx];
  }
  __syncthreads();
  for (int idx = tid; idx < 4096; idx += 256) {
    int dd = idx >> 6, k = idx & 63;
    ws[OFF_W3GTT + idx] = w_s[dd * 193 + 128 + k] * g[k];
  }
  uint32_t* w1b = (uint32_t*)(ws + OFF_W1B);
  uint32_t* w2b = (uint32_t*)(ws + OFF_W2B);
  for (int idx = tid; idx < 2048; idx += 256) {
    int dd = idx >> 5, kp = (idx & 31) * 2;
    w1b[idx] = pk2(w_s[dd * 193 + kp] * C2L,      w_s[dd * 193 + kp + 1] * C2L);
    w2b[idx] = pk2(w_s[dd * 193 + 64 + kp] * C2L, w_s[dd * 193 + 64 + kp + 1] * C2L);
  }
  if (tid < 64) {
    float wg = 0.f, wb = 0.f;
#pragma unroll
    for (int k = 0; k < 64; ++k) {
      float w = w_s[tid * 193 + 128 + k];
      wg = fmaf(w, g[k], wg);
      wb = fmaf(w, bln[k], wb);
    }
    ws[OFF_W3G + tid] = wg;
    ws[OFF_C0 + tid]  = C2L * (bij[tid] + wb);
  }
  if (tid == 0) {
    float s = 0.f;
    for (int k = 0; k < 64; ++k) s += wsum[k];
    ws[OFF_WSUMS] = s;
  }
}

// K1: one block per batch b (runs on XCD b%8). Stage+LN once; emit E16/E2 tiles,
// PA16 = C2L*LNE.w1 (bf16 [j][c][n]), PB16 = C2L*LNE.w2 (bf16 [t][d]).
__global__ __launch_bounds__(256) void k1_batch(
    const float* __restrict__ emb,
    const float* __restrict__ gg,
    const float* __restrict__ bb,
    float* __restrict__ ws) {
  int b = blockIdx.x;
  int tid = threadIdx.x;
  int wv = tid >> 6, lane = tid & 63, g = lane >> 4, c = lane & 15;

  __shared__ ushort LNE16[NIP * 64];   // 14336 B, swizzled
  char* e16g  = (char*)ws + OFF_E16  * 4 + b * TILEB;
  char* e2g   = (char*)ws + OFF_E2   * 4 + b * TILEB;
  char* pa16g = (char*)ws + OFF_PA16 * 4 + b * TILEB;
  ushort* pb16 = (ushort*)(ws + OFF_PB16);
  const float* eb = emb + b * NI * D;

  // stage: e -> E16(global), e^2 -> E2(global), LN(e) -> LNE16(LDS)
  for (int u = tid; u < NIP * 8; u += 256) {
    int r = u >> 3, cb = u & 7, kk = cb * 8;
    int4 pe, ps, pl;
    if (r < NI) {
      const float* sp = eb + r * 64 + kk;
      float4 f0 = *(const float4*)sp, f1 = *(const float4*)(sp + 4);
      float s  = f0.x + f0.y + f0.z + f0.w + f1.x + f1.y + f1.z + f1.w;
      float s2 = f0.x*f0.x + f0.y*f0.y + f0.z*f0.z + f0.w*f0.w
               + f1.x*f1.x + f1.y*f1.y + f1.z*f1.z + f1.w*f1.w;
#pragma unroll
      for (int off = 1; off < 8; off <<= 1) {
        s  += __shfl_xor(s, off, 64);
        s2 += __shfl_xor(s2, off, 64);
      }
      float mu  = s * (1.f / 64.f);
      float var = s2 * (1.f / 64.f) - mu * mu;
      float rsv = rsqrtf(var + LN_EPS);
      float4 g0 = *(const float4*)(gg + kk), g1v = *(const float4*)(gg + kk + 4);
      float4 b0 = *(const float4*)(bb + kk), b1v = *(const float4*)(bb + kk + 4);
      float l0 = fmaf((f0.x - mu) * rsv, g0.x, b0.x);
      float l1 = fmaf((f0.y - mu) * rsv, g0.y, b0.y);
      float l2 = fmaf((f0.z - mu) * rsv, g0.z, b0.z);
      float l3 = fmaf((f0.w - mu) * rsv, g0.w, b0.w);
      float l4 = fmaf((f1.x - mu) * rsv, g1v.x, b1v.x);
      float l5 = fmaf((f1.y - mu) * rsv, g1v.y, b1v.y);
      float l6 = fmaf((f1.z - mu) * rsv, g1v.z, b1v.z);
      float l7 = fmaf((f1.w - mu) * rsv, g1v.w, b1v.w);
      pe.x = pkt(f0.x, f0.y); pe.y = pkt(f0.z, f0.w);
      pe.z = pkt(f1.x, f1.y); pe.w = pkt(f1.z, f1.w);
      ps.x = pkt(f0.x*f0.x, f0.y*f0.y); ps.y = pkt(f0.z*f0.z, f0.w*f0.w);
      ps.z = pkt(f1.x*f1.x, f1.y*f1.y); ps.w = pkt(f1.z*f1.z, f1.w*f1.w);
      pl.x = pkt(l0, l1); pl.y = pkt(l2, l3);
      pl.z = pkt(l4, l5); pl.w = pkt(l6, l7);
    } else {
      pe = make_int4(0,0,0,0); ps = pe; pl = pe;
    }
    int sw = (r * 128 + cb * 16) ^ ((r & 7) << 4);
    *(int4*)(e16g + sw) = pe;
    *(int4*)(e2g + sw)  = ps;
    *(int4*)((char*)LNE16 + sw) = pl;
  }
  __syncthreads();

  // B-fragments
  bf8 bw1[4][2], bw2[4][2];
  {
    const ushort* w1b = (const ushort*)(ws + OFF_W1B);
    const ushort* w2b = (const ushort*)(ws + OFF_W2B);
#pragma unroll
    for (int n = 0; n < 4; ++n)
#pragma unroll
      for (int s = 0; s < 2; ++s) {
        bw1[n][s] = *(const bf8*)(w1b + (16 * n + c) * 64 + 8 * g + 32 * s);
        bw2[n][s] = *(const bf8*)(w2b + (16 * n + c) * 64 + 8 * g + 32 * s);
      }
  }

  // PA/PB GEMM over m-tiles (wave wv owns m = wv, wv+4)
  for (int m = wv; m < 7; m += 4) {
    bf8 a[2];
#pragma unroll
    for (int s = 0; s < 2; ++s) {
      int r = 16 * m + c;
      a[s] = *(bf8*)((char*)LNE16 + ((r * 128 + 16 * g + 64 * s) ^ ((r & 7) << 4)));
    }
    f32x4 pa[4], pbk[4];
#pragma unroll
    for (int n = 0; n < 4; ++n) { pa[n] = (f32x4)0.f; pbk[n] = (f32x4)0.f; }
#pragma unroll
    for (int s = 0; s < 2; ++s)
#pragma unroll
      for (int n = 0; n < 4; ++n) {
        pa[n]  = __builtin_amdgcn_mfma_f32_16x16x32_bf16(a[s], bw1[n][s], pa[n], 0, 0, 0);
        pbk[n] = __builtin_amdgcn_mfma_f32_16x16x32_bf16(a[s], bw2[n][s], pbk[n], 0, 0, 0);
      }
#pragma unroll
    for (int reg = 0; reg < 4; ++reg) {
      int j = 16 * m + 4 * g + reg;
      uint2 v;
      v.x = (uint32_t)pk2(pa[0][reg], pa[1][reg]);
      v.y = (uint32_t)pk2(pa[2][reg], pa[3][reg]);
      *(uint2*)(pa16g + j * 128 + c * 8) = v;     // [j][c][n], no swizzle
      if (j < NI) {
#pragma unroll
        for (int n = 0; n < 4; ++n)
          pb16[(b * NI + j) * 64 + 16 * n + c] = (ushort)f2bf(pbk[n][reg]);
      }
    }
  }
}

// K2: one block per (b, 4-i tile); wave wv owns i = i0+wv end-to-end.
// XCD swizzle: b = bid & 63 so all 25 blocks of batch b land on XCD b%8,
// where k1 left E16/E2/PA16 hot in that XCD's private L2.
__global__ __launch_bounds__(256, 4) void k2_main(
    const float* __restrict__ emb,
    const float* __restrict__ wsum,
    const float* __restrict__ bsum,
    const float* __restrict__ ws,
    float* __restrict__ out) {
  int bid = blockIdx.x;
  int b = bid & 63, itile = bid >> 6;
  int i0 = itile * IT;
  int tid = threadIdx.x;
  int wv = tid >> 6, lane = tid & 63, g = lane >> 4, c = lane & 15;
  int i = i0 + wv;

  __shared__ ushort E16[NIP * 64];   // 14336 B: bf16 e_j, swizzled
  __shared__ float rs2_s[IT][NIP];   // C2L*rs
  __shared__ float mrs2_s[IT][NIP];  // -C2L*mu*rs
  __shared__ float z_s[IT][NIP];     // z then alpha

  const char* e16g  = (const char*)ws + OFF_E16  * 4 + b * TILEB;
  const char* e2g   = (const char*)ws + OFF_E2   * 4 + b * TILEB;
  const char* pa16g = (const char*)ws + OFF_PA16 * 4 + b * TILEB;
  const ushort* pb16 = (const ushort*)(ws + OFF_PB16);

  // stage E16 (linear copy; swizzle baked in)
  for (int u = tid; u < TILEB / 16; u += 256)
    ((int4*)E16)[u] = ((const int4*)e16g)[u];
  __syncthreads();

  // ---- Gram stats (squares from global E2 tile) ----
  {
    bf8 aI[2], aIsq[2];
#pragma unroll
    for (int s = 0; s < 2; ++s) {
      int r = i0 + c;
      int sw = (r * 128 + 16 * g + 64 * s) ^ ((r & 7) << 4);
      aI[s]   = *(bf8*)((char*)E16 + sw);
      aIsq[s] = *(const bf8*)(e2g + sw);
    }
    for (int jt = wv; jt < 7; jt += 4) {
      f32x4 g1 = (f32x4)0.f, g2 = (f32x4)0.f;
#pragma unroll
      for (int s = 0; s < 2; ++s) {
        int r = 16 * jt + c;
        int sw = (r * 128 + 16 * g + 64 * s) ^ ((r & 7) << 4);
        bf8 aj  = *(bf8*)((char*)E16 + sw);
        bf8 ajs = *(const bf8*)(e2g + sw);
        g1 = __builtin_amdgcn_mfma_f32_16x16x32_bf16(aI[s],   aj,  g1, 0, 0, 0);
        g2 = __builtin_amdgcn_mfma_f32_16x16x32_bf16(aIsq[s], ajs, g2, 0, 0, 0);
      }
      if (g == 0) {
#pragma unroll
        for (int reg = 0; reg < 4; ++reg) {
          float mu  = g1[reg] * (1.f / 64.f);
          float v2  = g2[reg] * (1.f / 64.f);
          float var = v2 - mu * mu;
          float rsv = rsqrtf(var + LN_EPS);
          rs2_s[reg][16 * jt + c]  = C2L * rsv;
          mrs2_s[reg][16 * jt + c] = -C2L * mu * rsv;
        }
      }
    }
  }

  // ---- bw3 fragments (e_i o w3g) in registers ----
  bf8 bw3[4][2];
  {
    const float* ei = emb + (b * NI + i) * 64;
    float4 eif[4];
#pragma unroll
    for (int s = 0; s < 2; ++s) {
      eif[2*s]   = *(const float4*)(ei + 8 * g + 32 * s);
      eif[2*s+1] = *(const float4*)(ei + 8 * g + 32 * s + 4);
    }
    const float* w3 = ws + OFF_W3GTT;
#pragma unroll
    for (int n = 0; n < 4; ++n) {
      int d = 16 * n + c;
#pragma unroll
      for (int s = 0; s < 2; ++s) {
        const float* wp = w3 + d * 64 + 8 * g + 32 * s;
        float4 w0 = *(const float4*)wp, w1v = *(const float4*)(wp + 4);
        float4 e0 = eif[2*s], e1 = eif[2*s+1];
        int4 pk;
        pk.x = pkt(w0.x * e0.x, w0.y * e0.y);
        pk.y = pkt(w0.z * e0.z, w0.w * e0.w);
        pk.z = pkt(w1v.x * e1.x, w1v.y * e1.y);
        pk.w = pkt(w1v.z * e1.z, w1v.w * e1.w);
        bw3[n][s] = *(bf8*)&pk;
      }
    }
  }

  // per-lane epilogue constants
  float w3g_n[4], cst2_n[4], wsum_n[4];
#pragma unroll
  for (int n = 0; n < 4; ++n) {
    int d = 16 * n + c;
    float pbv = __uint_as_float(((uint32_t)pb16[(b * NI + i) * 64 + d]) << 16);
    w3g_n[n]  = ws[OFF_W3G + d];
    cst2_n[n] = pbv + ws[OFF_C0 + d];
    wsum_n[n] = wsum[d];
  }
  float zbase = ws[OFF_WSUMS] + bsum[0];

  __syncthreads();   // rs2/mrs2 ready

  // ---- pass Q: q3 = E*(e_i o w3g); PA from global b64; fused epilogue ----
#pragma unroll 2
  for (int m = 0; m < 7; ++m) {
    uint2 pav[4];
#pragma unroll
    for (int reg = 0; reg < 4; ++reg) {
      int j = 16 * m + 4 * g + reg;
      pav[reg] = *(const uint2*)(pa16g + j * 128 + c * 8);
    }
    f32x4 q3[4];
#pragma unroll
    for (int n = 0; n < 4; ++n) q3[n] = (f32x4)0.f;
#pragma unroll
    for (int s = 0; s < 2; ++s) {
      int r = 16 * m + c;
      int sw = (r * 128 + 16 * g + 64 * s) ^ ((r & 7) << 4);
      bf8 a = *(bf8*)((char*)E16 + sw);
#pragma unroll
      for (int n = 0; n < 4; ++n)
        q3[n] = __builtin_amdgcn_mfma_f32_16x16x32_bf16(a, bw3[n][s], q3[n], 0, 0, 0);
    }
    float rs2v[4], mrs2v[4];
#pragma unroll
    for (int reg = 0; reg < 4; ++reg) {
      rs2v[reg]  = rs2_s[wv][16 * m + 4 * g + reg];
      mrs2v[reg] = mrs2_s[wv][16 * m + 4 * g + reg];
    }
    float zacc[4] = {0.f, 0.f, 0.f, 0.f};
#pragma unroll
    for (int reg = 0; reg < 4; ++reg) {
      float paf[4];
      paf[0] = __uint_as_float(pav[reg].x << 16);
      paf[1] = __uint_as_float(pav[reg].x & 0xffff0000u);
      paf[2] = __uint_as_float(pav[reg].y << 16);
      paf[3] = __uint_as_float(pav[reg].y & 0xffff0000u);
#pragma unroll
      for (int n = 0; n < 4; ++n) {
        float X = fmaf(rs2v[reg], q3[n][reg],
                   fmaf(mrs2v[reg], w3g_n[n], paf[n] + cst2_n[n]));
        float ex = exp2f(X);                          // e^{2x}
        float rr = __builtin_amdgcn_rcpf(ex + 1.f);   // tanh = 1 - 2*rr
        zacc[reg] = fmaf(wsum_n[n], rr, zacc[reg]);
      }
    }
#pragma unroll
    for (int reg = 0; reg < 4; ++reg) {
      float zv = zacc[reg];
      zv += __shfl_xor(zv, 1, 64);
      zv += __shfl_xor(zv, 2, 64);
      zv += __shfl_xor(zv, 4, 64);
      zv += __shfl_xor(zv, 8, 64);
      if (c == 0)
        z_s[wv][16 * m + 4 * g + reg] = fmaf(-2.f, zv, zbase);
    }
  }

  // ---- softmax (per wave, own row) ----
  {
    int j0 = lane, j1 = lane + 64;
    bool v0 = (j0 != i);
    bool v1 = (j1 < NI) && (j1 != i);
    float z0 = z_s[wv][j0];
    float z1 = (j1 < NIP) ? z_s[wv][j1] : 0.f;
    z0 = v0 ? z0 : -__builtin_inff();
    z1 = v1 ? z1 : -__builtin_inff();
    float mx = fmaxf(z0, z1);
#pragma unroll
    for (int off = 32; off > 0; off >>= 1)
      mx = fmaxf(mx, __shfl_xor(mx, off, 64));
    float e0 = v0 ? __expf(z0 - mx) : 0.f;
    float e1 = v1 ? __expf(z1 - mx) : 0.f;
    float ss = e0 + e1;
#pragma unroll
    for (int off = 32; off > 0; off >>= 1)
      ss += __shfl_xor(ss, off, 64);
    float inv = 1.f / ss;
    z_s[wv][j0] = e0 * inv;
    if (j1 < NIP) z_s[wv][j1] = e1 * inv;
  }

  // ---- PV + epilogue (dual accumulators to halve the fma dep chain) ----
  {
    int kp = lane & 31, half = lane >> 5;
    float s0 = 0.f, s1 = 0.f, s0b = 0.f, s1b = 0.f;
    int jb = half * 50;
    for (int t = 0; t < 50; t += 2) {
      int j = jb + t, j2 = jb + t + 1;
      float al  = z_s[wv][j];
      float al2 = z_s[wv][j2];
      int sw  = (j * 128 + kp * 4) ^ ((j & 7) << 4);
      int sw2 = (j2 * 128 + kp * 4) ^ ((j2 & 7) << 4);
      uint32_t u  = *(const uint32_t*)((const char*)E16 + sw);
      uint32_t u2 = *(const uint32_t*)((const char*)E16 + sw2);
      s0  = fmaf(al,  __uint_as_float(u << 16), s0);
      s1  = fmaf(al,  __uint_as_float(u & 0xffff0000u), s1);
      s0b = fmaf(al2, __uint_as_float(u2 << 16), s0b);
      s1b = fmaf(al2, __uint_as_float(u2 & 0xffff0000u), s1b);
    }
    float sf0 = s0 + s0b, sf1 = s1 + s1b;
    sf0 += __shfl_xor(sf0, 32, 64);
    sf1 += __shfl_xor(sf1, 32, 64);
    if (half == 0) {
      const float* ei = emb + (b * NI + i) * 64;
      float e0 = ei[2 * kp], e1 = ei[2 * kp + 1];
      float c0 = fmaf(e0, sf0, e0 * e0);
      float c1 = fmaf(e1, sf1, e1 * e1);
      c0 = (c0 >= 0.f) ? c0 : 0.01f * c0;
      c1 = (c1 >= 0.f) ? c1 : 0.01f * c1;
      float2 o; o.x = c0; o.y = c1;
      *(float2*)(out + (b * NI + i) * 64 + 2 * kp) = o;
    }
  }
}

extern "C" void kernel_launch(void* const* d_in, const int* in_sizes, int n_in,
                              void* d_out, int out_size, void* d_ws, size_t ws_size,
                              hipStream_t stream) {
  const float* emb  = (const float*)d_in[0];
  const float* g    = (const float*)d_in[1];
  const float* bln  = (const float*)d_in[2];
  const float* w_ij = (const float*)d_in[3];
  const float* bij  = (const float*)d_in[4];
  const float* wsum = (const float*)d_in[5];
  const float* bsum = (const float*)d_in[6];
  float* ws  = (float*)d_ws;
  float* out = (float*)d_out;

  hipLaunchKernelGGL(k0_prep, dim3(1), dim3(256), 0, stream,
                     w_ij, g, bln, wsum, bij, ws);
  hipLaunchKernelGGL(k1_batch, dim3(BSZ), dim3(256), 0, stream,
                     emb, g, bln, ws);
  hipLaunchKernelGGL(k2_main, dim3(BSZ * NT2), dim3(256), 0, stream,
                     emb, wsum, bsum, ws, out);
}